// Round 1
// baseline (1215.606 us; speedup 1.0000x reference)
//
#include <hip/hip_runtime.h>

#define D 128
#define D4 32          // D / 4
#define EPS 1e-5f

// ---------------- zero workspace (ws is poisoned 0xAA before every launch) ----------------
__global__ __launch_bounds__(256) void zero_f4(float4* __restrict__ p, int n4) {
    int i = blockIdx.x * 256 + threadIdx.x;
    const int stride = gridDim.x * 256;
    for (; i < n4; i += stride) p[i] = make_float4(0.f, 0.f, 0.f, 0.f);
}

// ---------------- edge scatter-add: agg[dst[e]] += hpre[src[e]] ----------------
// 32 lanes per edge, float4 per lane (128 floats per edge). 8 edges per 256-thread block.
__global__ __launch_bounds__(256) void scatter_add(const float* __restrict__ hpre,
                                                   const int* __restrict__ src,
                                                   const int* __restrict__ dst,
                                                   float* __restrict__ agg, int nE) {
    const int t = threadIdx.x;
    const int lane = t & 31;
    const int e = blockIdx.x * 8 + (t >> 5);
    if (e >= nE) return;
    const int s = src[e];
    const int d = dst[e];
    float4 v = ((const float4*)hpre)[(size_t)s * D4 + lane];
    float* o = agg + (size_t)d * D + lane * 4;
    // unsafeAtomicAdd -> hardware global_atomic_add_f32 (no CAS loop)
    unsafeAtomicAdd(o + 0, v.x);
    unsafeAtomicAdd(o + 1, v.y);
    unsafeAtomicAdd(o + 2, v.z);
    unsafeAtomicAdd(o + 3, v.w);
}

// ---------------- GEMM: Y[r] = act(X[r] @ W + b) ----------------
// 32 rows/block staged in 16KB LDS; W (64KB) streamed from global (L1/L2 resident,
// shared across all blocks). Thread (tx,ty): rows ty*4..ty*4+3, cols 4*tx..4*tx+3.
// NOTE: X/Y intentionally NOT __restrict__ (in-place use when ws is small is
// row-partitioned by block and therefore safe).
template <bool RELU>
__global__ __launch_bounds__(256) void gemm_bias(const float* X,
                                                 const float* __restrict__ W,
                                                 const float* __restrict__ b,
                                                 float* Y, int nrows) {
    __shared__ float4 Hl[32 * D4];  // 16 KB
    const int t = threadIdx.x;
    const int tx = t & 31;
    const int ty = t >> 5;
    const int r0 = blockIdx.x * 32;

    const float4* X4 = (const float4*)X;
#pragma unroll
    for (int i = 0; i < 4; ++i) {
        int idx = i * 256 + t;          // 0..1023 -> row idx>>5, col4 idx&31
        int rr = r0 + (idx >> 5);
        float4 v = make_float4(0.f, 0.f, 0.f, 0.f);
        if (rr < nrows) v = X4[(size_t)rr * D4 + (idx & 31)];
        Hl[idx] = v;
    }
    __syncthreads();

    const float4* W4 = (const float4*)W;
    float4 acc[4];
#pragma unroll
    for (int i = 0; i < 4; ++i) acc[i] = make_float4(0.f, 0.f, 0.f, 0.f);

#pragma unroll 4
    for (int k = 0; k < D; k += 4) {
        float4 w0 = W4[(k + 0) * D4 + tx];
        float4 w1 = W4[(k + 1) * D4 + tx];
        float4 w2 = W4[(k + 2) * D4 + tx];
        float4 w3 = W4[(k + 3) * D4 + tx];
#pragma unroll
        for (int i = 0; i < 4; ++i) {
            float4 h = Hl[(ty * 4 + i) * D4 + (k >> 2)];
            acc[i].x = fmaf(h.x, w0.x, acc[i].x);
            acc[i].x = fmaf(h.y, w1.x, acc[i].x);
            acc[i].x = fmaf(h.z, w2.x, acc[i].x);
            acc[i].x = fmaf(h.w, w3.x, acc[i].x);
            acc[i].y = fmaf(h.x, w0.y, acc[i].y);
            acc[i].y = fmaf(h.y, w1.y, acc[i].y);
            acc[i].y = fmaf(h.z, w2.y, acc[i].y);
            acc[i].y = fmaf(h.w, w3.y, acc[i].y);
            acc[i].z = fmaf(h.x, w0.z, acc[i].z);
            acc[i].z = fmaf(h.y, w1.z, acc[i].z);
            acc[i].z = fmaf(h.z, w2.z, acc[i].z);
            acc[i].z = fmaf(h.w, w3.z, acc[i].z);
            acc[i].w = fmaf(h.x, w0.w, acc[i].w);
            acc[i].w = fmaf(h.y, w1.w, acc[i].w);
            acc[i].w = fmaf(h.z, w2.w, acc[i].w);
            acc[i].w = fmaf(h.w, w3.w, acc[i].w);
        }
    }

    const float4 bias = ((const float4*)b)[tx];
#pragma unroll
    for (int i = 0; i < 4; ++i) {
        int rr = r0 + ty * 4 + i;
        if (rr >= nrows) continue;
        float4 o;
        o.x = acc[i].x + bias.x;
        o.y = acc[i].y + bias.y;
        o.z = acc[i].z + bias.z;
        o.w = acc[i].w + bias.w;
        if (RELU) {
            o.x = fmaxf(o.x, 0.f);
            o.y = fmaxf(o.y, 0.f);
            o.z = fmaxf(o.z, 0.f);
            o.w = fmaxf(o.w, 0.f);
        }
        ((float4*)Y)[(size_t)rr * D4 + tx] = o;
    }
}

// ---------------- final GEMM fused with bias + relu + residual + LayerNorm ----------------
__global__ __launch_bounds__(256) void gemm_ln(const float* __restrict__ X,
                                               const float* __restrict__ W,
                                               const float* __restrict__ b,
                                               const float* __restrict__ Hres,
                                               const float* __restrict__ gamma,
                                               const float* __restrict__ beta,
                                               float* __restrict__ Y, int nrows) {
    __shared__ float4 Hl[32 * D4];  // 16 KB
    const int t = threadIdx.x;
    const int tx = t & 31;
    const int ty = t >> 5;
    const int r0 = blockIdx.x * 32;

    const float4* X4 = (const float4*)X;
#pragma unroll
    for (int i = 0; i < 4; ++i) {
        int idx = i * 256 + t;
        int rr = r0 + (idx >> 5);
        float4 v = make_float4(0.f, 0.f, 0.f, 0.f);
        if (rr < nrows) v = X4[(size_t)rr * D4 + (idx & 31)];
        Hl[idx] = v;
    }
    __syncthreads();

    const float4* W4 = (const float4*)W;
    float4 acc[4];
#pragma unroll
    for (int i = 0; i < 4; ++i) acc[i] = make_float4(0.f, 0.f, 0.f, 0.f);

#pragma unroll 4
    for (int k = 0; k < D; k += 4) {
        float4 w0 = W4[(k + 0) * D4 + tx];
        float4 w1 = W4[(k + 1) * D4 + tx];
        float4 w2 = W4[(k + 2) * D4 + tx];
        float4 w3 = W4[(k + 3) * D4 + tx];
#pragma unroll
        for (int i = 0; i < 4; ++i) {
            float4 h = Hl[(ty * 4 + i) * D4 + (k >> 2)];
            acc[i].x = fmaf(h.x, w0.x, acc[i].x);
            acc[i].x = fmaf(h.y, w1.x, acc[i].x);
            acc[i].x = fmaf(h.z, w2.x, acc[i].x);
            acc[i].x = fmaf(h.w, w3.x, acc[i].x);
            acc[i].y = fmaf(h.x, w0.y, acc[i].y);
            acc[i].y = fmaf(h.y, w1.y, acc[i].y);
            acc[i].y = fmaf(h.z, w2.y, acc[i].y);
            acc[i].y = fmaf(h.w, w3.y, acc[i].y);
            acc[i].z = fmaf(h.x, w0.z, acc[i].z);
            acc[i].z = fmaf(h.y, w1.z, acc[i].z);
            acc[i].z = fmaf(h.z, w2.z, acc[i].z);
            acc[i].z = fmaf(h.w, w3.z, acc[i].z);
            acc[i].w = fmaf(h.x, w0.w, acc[i].w);
            acc[i].w = fmaf(h.y, w1.w, acc[i].w);
            acc[i].w = fmaf(h.z, w2.w, acc[i].w);
            acc[i].w = fmaf(h.w, w3.w, acc[i].w);
        }
    }

    const float4 bias = ((const float4*)b)[tx];
    const float4 g4 = ((const float4*)gamma)[tx];
    const float4 be4 = ((const float4*)beta)[tx];

    float4 v[4];
    float sm[4], sq[4];
#pragma unroll
    for (int i = 0; i < 4; ++i) {
        int rr = r0 + ty * 4 + i;
        float4 a;
        a.x = fmaxf(acc[i].x + bias.x, 0.f);
        a.y = fmaxf(acc[i].y + bias.y, 0.f);
        a.z = fmaxf(acc[i].z + bias.z, 0.f);
        a.w = fmaxf(acc[i].w + bias.w, 0.f);
        float4 hp = make_float4(0.f, 0.f, 0.f, 0.f);
        if (rr < nrows) hp = ((const float4*)Hres)[(size_t)rr * D4 + tx];
        v[i].x = hp.x + a.x;
        v[i].y = hp.y + a.y;
        v[i].z = hp.z + a.z;
        v[i].w = hp.w + a.w;
        sm[i] = v[i].x + v[i].y + v[i].z + v[i].w;
        sq[i] = v[i].x * v[i].x + v[i].y * v[i].y + v[i].z * v[i].z + v[i].w * v[i].w;
    }

    // each row's 128 cols live on a contiguous 32-lane half-wave -> width-32 butterfly
#pragma unroll
    for (int m = 1; m < 32; m <<= 1) {
#pragma unroll
        for (int i = 0; i < 4; ++i) {
            sm[i] += __shfl_xor(sm[i], m, 32);
            sq[i] += __shfl_xor(sq[i], m, 32);
        }
    }

#pragma unroll
    for (int i = 0; i < 4; ++i) {
        int rr = r0 + ty * 4 + i;
        if (rr >= nrows) continue;
        float mu = sm[i] * (1.f / D);
        float var = sq[i] * (1.f / D) - mu * mu;
        float is = rsqrtf(var + EPS);
        float4 o;
        o.x = (v[i].x - mu) * is * g4.x + be4.x;
        o.y = (v[i].y - mu) * is * g4.y + be4.y;
        o.z = (v[i].z - mu) * is * g4.z + be4.z;
        o.w = (v[i].w - mu) * is * g4.w + be4.w;
        ((float4*)Y)[(size_t)rr * D4 + tx] = o;
    }
}

extern "C" void kernel_launch(void* const* d_in, const int* in_sizes, int n_in,
                              void* d_out, int out_size, void* d_ws, size_t ws_size,
                              hipStream_t stream) {
    const float* h     = (const float*)d_in[0];
    const int*   src   = (const int*)d_in[1];
    const int*   dst   = (const int*)d_in[2];
    const float* W_pre = (const float*)d_in[3];
    const float* b_pre = (const float*)d_in[4];
    const float* W1    = (const float*)d_in[5];
    const float* b1    = (const float*)d_in[6];
    const float* W2    = (const float*)d_in[7];
    const float* b2    = (const float*)d_in[8];
    const float* gamma = (const float*)d_in[9];
    const float* beta  = (const float*)d_in[10];
    float* out = (float*)d_out;

    const int nN = in_sizes[0] / D;   // 50000
    const int nE = in_sizes[1];       // 600000
    const size_t buf = (size_t)nN * D;

    float* hpre = (float*)d_ws;       // [nN, D]
    float* agg  = hpre + buf;         // [nN, D]
    // t1 gets its own buffer if ws allows; else in-place over agg (row-partitioned, safe)
    float* t1 = (ws_size >= 3 * buf * sizeof(float)) ? (agg + buf) : agg;

    const int rblocks = (nN + 31) / 32;

    zero_f4<<<2048, 256, 0, stream>>>((float4*)agg, (int)(buf / 4));
    gemm_bias<false><<<rblocks, 256, 0, stream>>>(h, W_pre, b_pre, hpre, nN);
    scatter_add<<<(nE + 7) / 8, 256, 0, stream>>>(hpre, src, dst, agg, nE);
    gemm_bias<true><<<rblocks, 256, 0, stream>>>(agg, W1, b1, t1, nN);
    gemm_ln<<<rblocks, 256, 0, stream>>>(t1, W2, b2, hpre, gamma, beta, out, nN);
}

// Round 2
// 306.081 us; speedup vs baseline: 3.9715x; 3.9715x over previous
//
#include <hip/hip_runtime.h>

#define D 128
#define D4 32          // D / 4
#define EPS 1e-5f
#define SCAN_CHUNK 1024   // elements per scan block (256 thr x 4)

// ---------------- zero int buffer (ws is poisoned 0xAA before every launch) ----------------
__global__ __launch_bounds__(256) void zero_i32(int* __restrict__ p, int n) {
    int i = blockIdx.x * 256 + threadIdx.x;
    const int stride = gridDim.x * 256;
    for (; i < n; i += stride) p[i] = 0;
}

__global__ __launch_bounds__(256) void zero_f4(float4* __restrict__ p, int n4) {
    int i = blockIdx.x * 256 + threadIdx.x;
    const int stride = gridDim.x * 256;
    for (; i < n4; i += stride) p[i] = make_float4(0.f, 0.f, 0.f, 0.f);
}

// ---------------- CSR build ----------------
__global__ __launch_bounds__(256) void hist_dst(const int* __restrict__ dst,
                                                int* __restrict__ counts, int nE) {
    int e = blockIdx.x * 256 + threadIdx.x;
    if (e < nE) atomicAdd(&counts[dst[e]], 1);
}

// per-chunk sums
__global__ __launch_bounds__(256) void scan_chunk_sums(const int* __restrict__ counts,
                                                       int* __restrict__ chunkSums, int n) {
    __shared__ int sh[256];
    const int t = threadIdx.x;
    const int base = blockIdx.x * SCAN_CHUNK + t * 4;
    int s = 0;
#pragma unroll
    for (int i = 0; i < 4; ++i) {
        int idx = base + i;
        if (idx < n) s += counts[idx];
    }
    sh[t] = s;
    __syncthreads();
    for (int off = 128; off > 0; off >>= 1) {
        if (t < off) sh[t] += sh[t + off];
        __syncthreads();
    }
    if (t == 0) chunkSums[blockIdx.x] = sh[0];
}

// single-wave exclusive scan of chunkSums (nChunks <= 64), in place; also offsets[nN]=nE
__global__ __launch_bounds__(64) void scan_top(int* __restrict__ chunkSums, int nChunks,
                                               int* __restrict__ offsets, int nN, int nE) {
    const int t = threadIdx.x;
    int orig = (t < nChunks) ? chunkSums[t] : 0;
    int v = orig;
#pragma unroll
    for (int off = 1; off < 64; off <<= 1) {
        int u = __shfl_up(v, off, 64);
        if (t >= off) v += u;
    }
    if (t < nChunks) chunkSums[t] = v - orig;   // exclusive
    if (t == 0) offsets[nN] = nE;
}

// per-chunk exclusive scan + chunk offset -> offsets[] and cursor[]
__global__ __launch_bounds__(256) void scan_final(const int* __restrict__ counts,
                                                  const int* __restrict__ chunkSums,
                                                  int* __restrict__ offsets,
                                                  int* __restrict__ cursor, int n) {
    __shared__ int sh[256];
    const int t = threadIdx.x;
    const int base = blockIdx.x * SCAN_CHUNK + t * 4;
    int c[4];
    int s = 0;
#pragma unroll
    for (int i = 0; i < 4; ++i) {
        int idx = base + i;
        c[i] = (idx < n) ? counts[idx] : 0;
        s += c[i];
    }
    sh[t] = s;
    __syncthreads();
    // Hillis-Steele inclusive scan over per-thread sums
    int val = s;
    for (int off = 1; off < 256; off <<= 1) {
        int u = (t >= off) ? sh[t - off] : 0;
        __syncthreads();
        val += u;
        sh[t] = val;
        __syncthreads();
    }
    int threadExcl = val - s + chunkSums[blockIdx.x];
    int run = threadExcl;
#pragma unroll
    for (int i = 0; i < 4; ++i) {
        int idx = base + i;
        if (idx < n) {
            offsets[idx] = run;
            cursor[idx] = run;
        }
        run += c[i];
    }
}

__global__ __launch_bounds__(256) void fill_edges(const int* __restrict__ src,
                                                  const int* __restrict__ dst,
                                                  int* __restrict__ cursor,
                                                  int* __restrict__ edge_src, int nE) {
    int e = blockIdx.x * 256 + threadIdx.x;
    if (e < nE) {
        int pos = atomicAdd(&cursor[dst[e]], 1);
        edge_src[pos] = src[e];
    }
}

// ---------------- gather segment-sum: agg[n] = sum over edges of hpre[edge_src] ----------------
// 32 lanes per node (float4 each), 8 nodes per 256-thread block.
__global__ __launch_bounds__(256) void gather_sum(const float* __restrict__ hpre,
                                                  const int* __restrict__ offsets,
                                                  const int* __restrict__ edge_src,
                                                  float* __restrict__ agg, int nN) {
    const int t = threadIdx.x;
    const int lane = t & 31;
    const int n = blockIdx.x * 8 + (t >> 5);
    if (n >= nN) return;
    const int beg = offsets[n];
    const int end = offsets[n + 1];
    const float4* H4 = (const float4*)hpre;
    float4 acc = make_float4(0.f, 0.f, 0.f, 0.f);
    int s_next = (beg < end) ? edge_src[beg] : 0;
    for (int j = beg; j < end; ++j) {
        int s = s_next;
        if (j + 1 < end) s_next = edge_src[j + 1];
        float4 v = H4[(size_t)s * D4 + lane];
        acc.x += v.x; acc.y += v.y; acc.z += v.z; acc.w += v.w;
    }
    ((float4*)agg)[(size_t)n * D4 + lane] = acc;
}

// ---------------- fallback: atomic scatter (used only if ws too small) ----------------
__global__ __launch_bounds__(256) void scatter_add(const float* __restrict__ hpre,
                                                   const int* __restrict__ src,
                                                   const int* __restrict__ dst,
                                                   float* __restrict__ agg, int nE) {
    const int t = threadIdx.x;
    const int lane = t & 31;
    const int e = blockIdx.x * 8 + (t >> 5);
    if (e >= nE) return;
    const int s = src[e];
    const int d = dst[e];
    float4 v = ((const float4*)hpre)[(size_t)s * D4 + lane];
    float* o = agg + (size_t)d * D + lane * 4;
    unsafeAtomicAdd(o + 0, v.x);
    unsafeAtomicAdd(o + 1, v.y);
    unsafeAtomicAdd(o + 2, v.z);
    unsafeAtomicAdd(o + 3, v.w);
}

// ---------------- GEMM: Y[r] = act(X[r] @ W + b) ----------------
template <bool RELU>
__global__ __launch_bounds__(256) void gemm_bias(const float* X,
                                                 const float* __restrict__ W,
                                                 const float* __restrict__ b,
                                                 float* Y, int nrows) {
    __shared__ float4 Hl[32 * D4];  // 16 KB
    const int t = threadIdx.x;
    const int tx = t & 31;
    const int ty = t >> 5;
    const int r0 = blockIdx.x * 32;

    const float4* X4 = (const float4*)X;
#pragma unroll
    for (int i = 0; i < 4; ++i) {
        int idx = i * 256 + t;
        int rr = r0 + (idx >> 5);
        float4 v = make_float4(0.f, 0.f, 0.f, 0.f);
        if (rr < nrows) v = X4[(size_t)rr * D4 + (idx & 31)];
        Hl[idx] = v;
    }
    __syncthreads();

    const float4* W4 = (const float4*)W;
    float4 acc[4];
#pragma unroll
    for (int i = 0; i < 4; ++i) acc[i] = make_float4(0.f, 0.f, 0.f, 0.f);

#pragma unroll 4
    for (int k = 0; k < D; k += 4) {
        float4 w0 = W4[(k + 0) * D4 + tx];
        float4 w1 = W4[(k + 1) * D4 + tx];
        float4 w2 = W4[(k + 2) * D4 + tx];
        float4 w3 = W4[(k + 3) * D4 + tx];
#pragma unroll
        for (int i = 0; i < 4; ++i) {
            float4 h = Hl[(ty * 4 + i) * D4 + (k >> 2)];
            acc[i].x = fmaf(h.x, w0.x, acc[i].x);
            acc[i].x = fmaf(h.y, w1.x, acc[i].x);
            acc[i].x = fmaf(h.z, w2.x, acc[i].x);
            acc[i].x = fmaf(h.w, w3.x, acc[i].x);
            acc[i].y = fmaf(h.x, w0.y, acc[i].y);
            acc[i].y = fmaf(h.y, w1.y, acc[i].y);
            acc[i].y = fmaf(h.z, w2.y, acc[i].y);
            acc[i].y = fmaf(h.w, w3.y, acc[i].y);
            acc[i].z = fmaf(h.x, w0.z, acc[i].z);
            acc[i].z = fmaf(h.y, w1.z, acc[i].z);
            acc[i].z = fmaf(h.z, w2.z, acc[i].z);
            acc[i].z = fmaf(h.w, w3.z, acc[i].z);
            acc[i].w = fmaf(h.x, w0.w, acc[i].w);
            acc[i].w = fmaf(h.y, w1.w, acc[i].w);
            acc[i].w = fmaf(h.z, w2.w, acc[i].w);
            acc[i].w = fmaf(h.w, w3.w, acc[i].w);
        }
    }

    const float4 bias = ((const float4*)b)[tx];
#pragma unroll
    for (int i = 0; i < 4; ++i) {
        int rr = r0 + ty * 4 + i;
        if (rr >= nrows) continue;
        float4 o;
        o.x = acc[i].x + bias.x;
        o.y = acc[i].y + bias.y;
        o.z = acc[i].z + bias.z;
        o.w = acc[i].w + bias.w;
        if (RELU) {
            o.x = fmaxf(o.x, 0.f);
            o.y = fmaxf(o.y, 0.f);
            o.z = fmaxf(o.z, 0.f);
            o.w = fmaxf(o.w, 0.f);
        }
        ((float4*)Y)[(size_t)rr * D4 + tx] = o;
    }
}

// ---------------- final GEMM fused with bias + relu + residual + LayerNorm ----------------
__global__ __launch_bounds__(256) void gemm_ln(const float* __restrict__ X,
                                               const float* __restrict__ W,
                                               const float* __restrict__ b,
                                               const float* __restrict__ Hres,
                                               const float* __restrict__ gamma,
                                               const float* __restrict__ beta,
                                               float* __restrict__ Y, int nrows) {
    __shared__ float4 Hl[32 * D4];  // 16 KB
    const int t = threadIdx.x;
    const int tx = t & 31;
    const int ty = t >> 5;
    const int r0 = blockIdx.x * 32;

    const float4* X4 = (const float4*)X;
#pragma unroll
    for (int i = 0; i < 4; ++i) {
        int idx = i * 256 + t;
        int rr = r0 + (idx >> 5);
        float4 v = make_float4(0.f, 0.f, 0.f, 0.f);
        if (rr < nrows) v = X4[(size_t)rr * D4 + (idx & 31)];
        Hl[idx] = v;
    }
    __syncthreads();

    const float4* W4 = (const float4*)W;
    float4 acc[4];
#pragma unroll
    for (int i = 0; i < 4; ++i) acc[i] = make_float4(0.f, 0.f, 0.f, 0.f);

#pragma unroll 4
    for (int k = 0; k < D; k += 4) {
        float4 w0 = W4[(k + 0) * D4 + tx];
        float4 w1 = W4[(k + 1) * D4 + tx];
        float4 w2 = W4[(k + 2) * D4 + tx];
        float4 w3 = W4[(k + 3) * D4 + tx];
#pragma unroll
        for (int i = 0; i < 4; ++i) {
            float4 h = Hl[(ty * 4 + i) * D4 + (k >> 2)];
            acc[i].x = fmaf(h.x, w0.x, acc[i].x);
            acc[i].x = fmaf(h.y, w1.x, acc[i].x);
            acc[i].x = fmaf(h.z, w2.x, acc[i].x);
            acc[i].x = fmaf(h.w, w3.x, acc[i].x);
            acc[i].y = fmaf(h.x, w0.y, acc[i].y);
            acc[i].y = fmaf(h.y, w1.y, acc[i].y);
            acc[i].y = fmaf(h.z, w2.y, acc[i].y);
            acc[i].y = fmaf(h.w, w3.y, acc[i].y);
            acc[i].z = fmaf(h.x, w0.z, acc[i].z);
            acc[i].z = fmaf(h.y, w1.z, acc[i].z);
            acc[i].z = fmaf(h.z, w2.z, acc[i].z);
            acc[i].z = fmaf(h.w, w3.z, acc[i].z);
            acc[i].w = fmaf(h.x, w0.w, acc[i].w);
            acc[i].w = fmaf(h.y, w1.w, acc[i].w);
            acc[i].w = fmaf(h.z, w2.w, acc[i].w);
            acc[i].w = fmaf(h.w, w3.w, acc[i].w);
        }
    }

    const float4 bias = ((const float4*)b)[tx];
    const float4 g4 = ((const float4*)gamma)[tx];
    const float4 be4 = ((const float4*)beta)[tx];

    float4 v[4];
    float sm[4], sq[4];
#pragma unroll
    for (int i = 0; i < 4; ++i) {
        int rr = r0 + ty * 4 + i;
        float4 a;
        a.x = fmaxf(acc[i].x + bias.x, 0.f);
        a.y = fmaxf(acc[i].y + bias.y, 0.f);
        a.z = fmaxf(acc[i].z + bias.z, 0.f);
        a.w = fmaxf(acc[i].w + bias.w, 0.f);
        float4 hp = make_float4(0.f, 0.f, 0.f, 0.f);
        if (rr < nrows) hp = ((const float4*)Hres)[(size_t)rr * D4 + tx];
        v[i].x = hp.x + a.x;
        v[i].y = hp.y + a.y;
        v[i].z = hp.z + a.z;
        v[i].w = hp.w + a.w;
        sm[i] = v[i].x + v[i].y + v[i].z + v[i].w;
        sq[i] = v[i].x * v[i].x + v[i].y * v[i].y + v[i].z * v[i].z + v[i].w * v[i].w;
    }

#pragma unroll
    for (int m = 1; m < 32; m <<= 1) {
#pragma unroll
        for (int i = 0; i < 4; ++i) {
            sm[i] += __shfl_xor(sm[i], m, 32);
            sq[i] += __shfl_xor(sq[i], m, 32);
        }
    }

#pragma unroll
    for (int i = 0; i < 4; ++i) {
        int rr = r0 + ty * 4 + i;
        if (rr >= nrows) continue;
        float mu = sm[i] * (1.f / D);
        float var = sq[i] * (1.f / D) - mu * mu;
        float is = rsqrtf(var + EPS);
        float4 o;
        o.x = (v[i].x - mu) * is * g4.x + be4.x;
        o.y = (v[i].y - mu) * is * g4.y + be4.y;
        o.z = (v[i].z - mu) * is * g4.z + be4.z;
        o.w = (v[i].w - mu) * is * g4.w + be4.w;
        ((float4*)Y)[(size_t)rr * D4 + tx] = o;
    }
}

extern "C" void kernel_launch(void* const* d_in, const int* in_sizes, int n_in,
                              void* d_out, int out_size, void* d_ws, size_t ws_size,
                              hipStream_t stream) {
    const float* h     = (const float*)d_in[0];
    const int*   src   = (const int*)d_in[1];
    const int*   dst   = (const int*)d_in[2];
    const float* W_pre = (const float*)d_in[3];
    const float* b_pre = (const float*)d_in[4];
    const float* W1    = (const float*)d_in[5];
    const float* b1    = (const float*)d_in[6];
    const float* W2    = (const float*)d_in[7];
    const float* b2    = (const float*)d_in[8];
    const float* gamma = (const float*)d_in[9];
    const float* beta  = (const float*)d_in[10];
    float* out = (float*)d_out;

    const int nN = in_sizes[0] / D;   // 50000
    const int nE = in_sizes[1];       // 600000
    const size_t buf = (size_t)nN * D;

    // ---- workspace layout ----
    float* hpre = (float*)d_ws;            // [nN, D]
    float* agg  = hpre + buf;              // [nN, D]
    int* edge_src  = (int*)(agg + buf);    // [nE]
    int* offsets   = edge_src + nE;        // [nN+1]
    int* cursor    = offsets + nN + 1;     // [nN]
    int* counts    = cursor + nN;          // [nN]
    int* chunkSums = counts + nN;          // [64]
    size_t csr_needed = (char*)(chunkSums + 64) - (char*)d_ws;
    float* t1 = (ws_size >= csr_needed + buf * sizeof(float)) ? (float*)(chunkSums + 64) : agg;

    const int rblocks = (nN + 31) / 32;
    const int nChunks = (nN + SCAN_CHUNK - 1) / SCAN_CHUNK;   // 49 for nN=50000

    if (ws_size >= csr_needed && nChunks <= 64) {
        // ---- CSR build ----
        zero_i32<<<64, 256, 0, stream>>>(counts, nN);
        hist_dst<<<(nE + 255) / 256, 256, 0, stream>>>(dst, counts, nE);
        scan_chunk_sums<<<nChunks, 256, 0, stream>>>(counts, chunkSums, nN);
        scan_top<<<1, 64, 0, stream>>>(chunkSums, nChunks, offsets, nN, nE);
        scan_final<<<nChunks, 256, 0, stream>>>(counts, chunkSums, offsets, cursor, nN);
        fill_edges<<<(nE + 255) / 256, 256, 0, stream>>>(src, dst, cursor, edge_src, nE);
        // ---- compute ----
        gemm_bias<false><<<rblocks, 256, 0, stream>>>(h, W_pre, b_pre, hpre, nN);
        gather_sum<<<(nN + 7) / 8, 256, 0, stream>>>(hpre, offsets, edge_src, agg, nN);
    } else {
        // fallback: atomic scatter
        zero_f4<<<2048, 256, 0, stream>>>((float4*)agg, (int)(buf / 4));
        gemm_bias<false><<<rblocks, 256, 0, stream>>>(h, W_pre, b_pre, hpre, nN);
        scatter_add<<<(nE + 7) / 8, 256, 0, stream>>>(hpre, src, dst, agg, nE);
    }

    gemm_bias<true><<<rblocks, 256, 0, stream>>>(agg, W1, b1, t1, nN);
    gemm_ln<<<rblocks, 256, 0, stream>>>(t1, W2, b2, hpre, gamma, beta, out, nN);
}